// Round 11
// baseline (1193.191 us; speedup 1.0000x reference)
//
#include <hip/hip_runtime.h>
#include <stdint.h>

// Mamba forward, MI355X. Round 11:
//  - logits: m201-style 8-phase 256x256 BK=64 kernel. 512 thr / 8 waves
//    (2Mx4N, per-wave 128x64), 128KB LDS dbuf, BK split into 2 kk-planes of
//    32 (each plane = r10's 0-conflict swizzle layout). 4 phases/K-tile,
//    counted vmcnt(4) at p1/p3 ends (before closing barrier -> cross-wave
//    safe), 1 half-tile staged per phase, setprio around MFMA clusters.
//    Ledger: 2-phase d2=257/259, d3=266, 128sq@occ3=300, spill=724+.
//  - layers unchanged from r10 (1134us best): PIPELINE3, split-K16, dt-bf16.

#define D_MODEL 768
#define N_LAYER 4
#define VOCAB 50257
#define D_STATE 16
#define D_INNER 1536
#define DT_RANK 48
#define LSEQ 2048
#define TCHUNK 64
#define NCHUNK 32

#define EMB_E 39321600L            // 51200*768
#define W1E 2359296L               // 3072*768
#define W2E 196608L                // 128*1536
#define W3E 98304L                 // 1536*64
#define W4E 1179648L               // 768*1536
#define PERL (W1E + W2E + W3E + W4E)
#define TOTCVT (EMB_E + 4 * PERL)

typedef unsigned short u16;
typedef __attribute__((ext_vector_type(8))) short short8;
typedef __attribute__((ext_vector_type(4))) float f32x4;
typedef __attribute__((ext_vector_type(4))) unsigned short us4;

__device__ __forceinline__ u16 f2bf(float f) {
  unsigned int x = __float_as_uint(f);
  x += 0x7fffu + ((x >> 16) & 1u);   // RNE
  return (u16)(x >> 16);
}
__device__ __forceinline__ float bf2f(u16 v) {
  return __uint_as_float(((unsigned int)v) << 16);
}
__device__ __forceinline__ void gl16(const void* g, void* l) {
  __builtin_amdgcn_global_load_lds((const __attribute__((address_space(1))) void*)g,
                                   (__attribute__((address_space(3))) void*)l, 16, 0, 0);
}

// 3-deep counted-vmcnt K-loop (128x128 tile kernels; 4 loads/stage).
#define PIPELINE3(NT)                                                         \
  STAGE(0, 0);                                                                \
  if ((NT) > 1) STAGE(32, 1);                                                 \
  if ((NT) > 2) STAGE(64, 2);                                                 \
  {                                                                           \
    int cur = 0;                                                              \
    for (int t = 0; t < (NT); t++) {                                          \
      int rem = (NT) - 1 - t;                                                 \
      if (rem >= 2)      { asm volatile("s_waitcnt vmcnt(8)" ::: "memory"); } \
      else if (rem == 1) { asm volatile("s_waitcnt vmcnt(4)" ::: "memory"); } \
      else               { asm volatile("s_waitcnt vmcnt(0)" ::: "memory"); } \
      asm volatile("s_barrier" ::: "memory");                                 \
      short8 af[4], bfr[4];                                                   \
      _Pragma("unroll")                                                       \
      for (int i = 0; i < 4; i++)                                             \
        af[i] = *(const short8*)(&lA[cur][(wm + i * 16 + fr) * 32 + kh]);     \
      _Pragma("unroll")                                                       \
      for (int j = 0; j < 4; j++)                                             \
        bfr[j] = *(const short8*)(&lB[cur][(wn + j * 16 + fr) * 32 + kh]);    \
      asm volatile("s_waitcnt lgkmcnt(0)" ::: "memory");                      \
      asm volatile("s_barrier" ::: "memory");                                 \
      if (t + 3 < (NT)) STAGE((t + 3) * 32, cur);                             \
      __builtin_amdgcn_s_setprio(1);                                          \
      _Pragma("unroll")                                                       \
      for (int i = 0; i < 4; i++)                                             \
        _Pragma("unroll")                                                     \
        for (int j = 0; j < 4; j++)                                           \
          acc[i][j] = __builtin_amdgcn_mfma_f32_16x16x32_bf16(af[i], bfr[j],  \
                                                              acc[i][j], 0, 0, 0); \
      __builtin_amdgcn_s_setprio(0);                                          \
      cur = (cur == 2) ? 0 : cur + 1;                                         \
    }                                                                         \
  }

// ---------------- upfront convert: emb + all layer weights -> bf16 arena -----
__global__ void k_convert_all(const float* __restrict__ emb, const float* __restrict__ in_w,
                              const float* __restrict__ xp_w, const float* __restrict__ dt_w,
                              const float* __restrict__ out_w, u16* __restrict__ dst) {
  long i0 = ((long)blockIdx.x * 256 + threadIdx.x) * 4;
  if (i0 >= TOTCVT) return;
  us4 o;
#pragma unroll
  for (int q = 0; q < 4; q++) {
    long i = i0 + q;
    float v;
    if (i < EMB_E) {
      long n = i / D_MODEL, k = i % D_MODEL;
      v = (n < VOCAB) ? emb[n * D_MODEL + k] : 0.0f;
    } else {
      long j = i - EMB_E;
      int l = (int)(j / PERL);
      long m = j % PERL;
      if (m < W1E) {
        v = in_w[(long)l * W1E + m];
      } else if (m < W1E + W2E) {
        long mm = m - W1E;
        long n = mm / D_INNER, k = mm % D_INNER;
        v = (n < 80) ? xp_w[(long)l * 80 * D_INNER + n * D_INNER + k] : 0.0f;
      } else if (m < W1E + W2E + W3E) {
        long mm = m - (W1E + W2E);
        long n = mm / 64, k = mm % 64;
        v = (k < DT_RANK) ? dt_w[(long)l * D_INNER * DT_RANK + n * DT_RANK + k] : 0.0f;
      } else {
        long mm = m - (W1E + W2E + W3E);
        v = out_w[(long)l * W4E + mm];
      }
    }
    o[q] = f2bf(v);
  }
  *(us4*)(dst + i0) = o;
}

// ---------------- embed + rmsnorm(layer0) ------------------------------------
__global__ void k_embed_rms(const int* __restrict__ idx, const float* __restrict__ emb,
                            const float* __restrict__ w, float* __restrict__ x,
                            u16* __restrict__ xnb) {
  int t = blockIdx.x, tid = threadIdx.x;
  __shared__ float red[256];
  const float* src = emb + (long)idx[t] * D_MODEL;
  float g[3];
  float s = 0.0f;
#pragma unroll
  for (int q = 0; q < 3; q++) {
    g[q] = src[tid + q * 256];
    s += g[q] * g[q];
  }
  red[tid] = s; __syncthreads();
  for (int o = 128; o > 0; o >>= 1) { if (tid < o) red[tid] += red[tid + o]; __syncthreads(); }
  float scale = rsqrtf(red[0] / (float)D_MODEL + 1e-5f);
#pragma unroll
  for (int q = 0; q < 3; q++) {
    int c = tid + q * 256;
    x[(long)t * D_MODEL + c] = g[q];
    xnb[(long)t * D_MODEL + c] = f2bf(g[q] * scale * w[c]);
  }
}

// ---------------- reduce out_proj partials + residual + rmsnorm --------------
__global__ void k_rms_red(const float* __restrict__ part, const float* __restrict__ w,
                          float* __restrict__ x, u16* __restrict__ xnb) {
  int t = blockIdx.x, tid = threadIdx.x;
  __shared__ float red[256];
  float g[3];
  float s = 0.0f;
#pragma unroll
  for (int q = 0; q < 3; q++) {
    int c = tid + q * 256;
    long off = (long)t * D_MODEL + c;
    float v = x[off];
#pragma unroll
    for (int p = 0; p < 4; p++) v += part[(size_t)p * LSEQ * D_MODEL + off];
    g[q] = v;
    s += v * v;
  }
  red[tid] = s; __syncthreads();
  for (int o = 128; o > 0; o >>= 1) { if (tid < o) red[tid] += red[tid + o]; __syncthreads(); }
  float scale = rsqrtf(red[0] / (float)D_MODEL + 1e-5f);
#pragma unroll
  for (int q = 0; q < 3; q++) {
    int c = tid + q * 256;
    x[(long)t * D_MODEL + c] = g[q];
    xnb[(long)t * D_MODEL + c] = f2bf(g[q] * scale * w[c]);
  }
}

// ---------------- 128x128 3-deep GEMM: C = A(M,K) * W(N,K)^T -----------------
// EPI: 1 = softplus(acc+bias[col]) -> bf16, 2 = bf16 store
template<int EPI>
__global__ __launch_bounds__(256) void k_gemm2(
    const u16* __restrict__ A, const u16* __restrict__ W, void* __restrict__ Cv,
    const float* __restrict__ bias, int N, int K, int lda, int ldb, int ldc) {
  __shared__ u16 lA[3][128 * 32];
  __shared__ u16 lB[3][128 * 32];
  const int gx = gridDim.x, gy = gridDim.y;
  int id = blockIdx.x + gx * blockIdx.y;
  int q8 = (gx * gy) >> 3;
  int v = (id & 7) * q8 + (id >> 3);
  const int bx = v / gy, by = v % gy;
  const int brow = by * 128, bcol = bx * 128;
  const int tid = threadIdx.x, wid = tid >> 6, lane = tid & 63;
  const int wm = (wid >> 1) * 64, wn = (wid & 1) * 64;
  const int fr = lane & 15, fq = lane >> 4;
  const int kh = 8 * (fq ^ ((fr >> 1) & 3));
  const int srow = tid >> 2;
  const int lcol = (tid & 3) * 8;
  const int scol = 8 * ((tid & 3) ^ ((srow >> 1) & 3));
  const u16* ga0 = A + (size_t)(brow + srow) * lda + scol;
  const u16* ga1 = A + (size_t)(brow + srow + 64) * lda + scol;
  const u16* gb0 = W + (size_t)(bcol + srow) * ldb + scol;
  const u16* gb1 = W + (size_t)(bcol + srow + 64) * ldb + scol;
  const int lo = srow * 32 + lcol;

  f32x4 acc[4][4];
#pragma unroll
  for (int i = 0; i < 4; i++)
#pragma unroll
    for (int j = 0; j < 4; j++)
#pragma unroll
      for (int r = 0; r < 4; r++) acc[i][j][r] = 0.0f;

  auto STAGE = [&](int k0, int b) {
    gl16(ga0 + k0, &lA[b][lo]);
    gl16(ga1 + k0, &lA[b][lo + 2048]);
    gl16(gb0 + k0, &lB[b][lo]);
    gl16(gb1 + k0, &lB[b][lo + 2048]);
  };

  PIPELINE3(K / 32);

#pragma unroll
  for (int i = 0; i < 4; i++)
#pragma unroll
    for (int j = 0; j < 4; j++) {
      int col = bcol + wn + j * 16 + fr;
      if (col < N) {
#pragma unroll
        for (int r = 0; r < 4; r++) {
          int row = brow + wm + i * 16 + fq * 4 + r;
          float val = acc[i][j][r];
          if (EPI == 1) {
            val += bias[col];
            val = (val > 20.0f) ? val : log1pf(__expf(val));
            ((u16*)Cv)[(size_t)row * ldc + col] = f2bf(val);
          } else {
            ((u16*)Cv)[(size_t)row * ldc + col] = f2bf(val);
          }
        }
      }
    }
}

// ---------------- split-K partial GEMM (3-deep) ------------------------------
__global__ __launch_bounds__(256) void k_gemm_part(
    const u16* __restrict__ A, const u16* __restrict__ W, float* __restrict__ Cp,
    int N, int Ks, int lda, int ldb, int ldc) {
  __shared__ u16 lA[3][128 * 32];
  __shared__ u16 lB[3][128 * 32];
  const int gx = gridDim.x, gy = gridDim.y;
  int id = blockIdx.x + gx * blockIdx.y;
  int q8 = (gx * gy) >> 3;
  int v = (id & 7) * q8 + (id >> 3);
  const int bx = v / gy, by = v % gy;
  const int brow = by * 128, bcol = bx * 128;
  const int koff = blockIdx.z * Ks;
  const int tid = threadIdx.x, wid = tid >> 6, lane = tid & 63;
  const int wm = (wid >> 1) * 64, wn = (wid & 1) * 64;
  const int fr = lane & 15, fq = lane >> 4;
  const int kh = 8 * (fq ^ ((fr >> 1) & 3));
  const int srow = tid >> 2;
  const int lcol = (tid & 3) * 8;
  const int scol = 8 * ((tid & 3) ^ ((srow >> 1) & 3));
  const u16* ga0 = A + (size_t)(brow + srow) * lda + koff + scol;
  const u16* ga1 = A + (size_t)(brow + srow + 64) * lda + koff + scol;
  const u16* gb0 = W + (size_t)(bcol + srow) * ldb + koff + scol;
  const u16* gb1 = W + (size_t)(bcol + srow + 64) * ldb + koff + scol;
  const int lo = srow * 32 + lcol;

  f32x4 acc[4][4];
#pragma unroll
  for (int i = 0; i < 4; i++)
#pragma unroll
    for (int j = 0; j < 4; j++)
#pragma unroll
      for (int r = 0; r < 4; r++) acc[i][j][r] = 0.0f;

  auto STAGE = [&](int k0, int b) {
    gl16(ga0 + k0, &lA[b][lo]);
    gl16(ga1 + k0, &lA[b][lo + 2048]);
    gl16(gb0 + k0, &lB[b][lo]);
    gl16(gb1 + k0, &lB[b][lo + 2048]);
  };

  PIPELINE3(Ks / 32);

  float* Cz = Cp + (size_t)blockIdx.z * LSEQ * ldc;
#pragma unroll
  for (int i = 0; i < 4; i++)
#pragma unroll
    for (int j = 0; j < 4; j++) {
      int col = bcol + wn + j * 16 + fr;
      if (col < N) {
#pragma unroll
        for (int r = 0; r < 4; r++) {
          int row = brow + wm + i * 16 + fq * 4 + r;
          Cz[(size_t)row * ldc + col] = acc[i][j][r];
        }
      }
    }
}

// ---------------- logits GEMM: 8-phase 256x256 BK=64 (m201 port) -------------
// 8 M-tiles x 200 N-tiles = 1600 blocks; XCD: ct = xcd*25 + slot/8, rt inner.
// LDS: [buf][kk-plane][256 rows x 32], each plane uses the verified swizzle.
// Per K-tile: 4 phases {ds_read frags; stage 1 half-tile of kt+1; barrier;
// MFMA x16 (setprio); [vmcnt(4) at p1/p3] barrier}. Loads never drain to 0.
__global__ __launch_bounds__(512, 2) void k_gemm_logits8(
    const u16* __restrict__ A, const u16* __restrict__ W, float* __restrict__ C,
    float* __restrict__ part) {
  __shared__ u16 lA[2][2][256 * 32];
  __shared__ u16 lB[2][2][256 * 32];
  const int b = blockIdx.x;
  const int xcd = b & 7, slot = b >> 3;
  const int ct = xcd * 25 + (slot >> 3), rt = slot & 7;
  const int brow = rt * 256, bcol = ct * 256;
  const int tid = threadIdx.x, wid = tid >> 6, lane = tid & 63;
  const int wm = (wid >> 2) * 128, wn = (wid & 3) * 64;
  const int fr = lane & 15, fq = lane >> 4;
  const int kh = 8 * (fq ^ ((fr >> 1) & 3));
  const int srow = tid >> 2;                       // 0..127
  const int sslot = (tid & 3) * 8;                 // linear LDS slot
  const int scol = 8 * ((tid & 3) ^ ((tid >> 3) & 3));  // swizzled global slot
  const u16* gA = A + (size_t)(brow + srow) * D_MODEL + scol;
  const u16* gB = W + (size_t)(bcol + srow) * D_MODEL + scol;
  const int lo = srow * 32 + sslot;

  f32x4 acc[8][4];
#pragma unroll
  for (int i = 0; i < 8; i++)
#pragma unroll
    for (int j = 0; j < 4; j++)
#pragma unroll
      for (int r = 0; r < 4; r++) acc[i][j][r] = 0.0f;

  // stage one kk-half-tile (256 rows x 32 cols) : 2 gload_lds per thread
  auto STG = [&](const u16* g, u16* lp, int kt, int kk) {
    const u16* s = g + (size_t)kt * 64 + kk * 32;
    gl16(s, lp + lo);
    gl16(s + (size_t)128 * D_MODEL, lp + lo + 4096);
  };

  // prologue: all 4 half-tiles of kt=0, order kh0(A,B) then kh1(A,B)
  STG(gA, &lA[0][0][0], 0, 0);
  STG(gB, &lB[0][0][0], 0, 0);
  STG(gA, &lA[0][1][0], 0, 1);
  STG(gB, &lB[0][1][0], 0, 1);
  asm volatile("s_waitcnt vmcnt(4)" ::: "memory");
  asm volatile("s_barrier" ::: "memory");

  const int NT = D_MODEL / 64;   // 12 K-tiles
  for (int kt = 0; kt < NT; kt++) {
    const int bb = kt & 1;
    const u16* la0 = &lA[bb][0][0];
    const u16* la1 = &lA[bb][1][0];
    const u16* lb0 = &lB[bb][0][0];
    const u16* lb1 = &lB[bb][1][0];
    u16* na0 = &lA[bb ^ 1][0][0];
    u16* na1 = &lA[bb ^ 1][1][0];
    u16* nb0 = &lB[bb ^ 1][0][0];
    u16* nb1 = &lB[bb ^ 1][1][0];
    const bool more = (kt + 1 < NT);
    short8 af[4], bf[4];

    // ---- phase 0: kk0, i-half 0 (+ B kk0 frags) ----
#pragma unroll
    for (int i = 0; i < 4; i++)
      af[i] = *(const short8*)(la0 + (wm + i * 16 + fr) * 32 + kh);
#pragma unroll
    for (int j = 0; j < 4; j++)
      bf[j] = *(const short8*)(lb0 + (wn + j * 16 + fr) * 32 + kh);
    if (more) STG(gA, na0, kt + 1, 0);
    asm volatile("s_barrier" ::: "memory");
    asm volatile("s_waitcnt lgkmcnt(0)" ::: "memory");
    __builtin_amdgcn_s_setprio(1);
#pragma unroll
    for (int i = 0; i < 4; i++)
#pragma unroll
      for (int j = 0; j < 4; j++)
        acc[i][j] = __builtin_amdgcn_mfma_f32_16x16x32_bf16(af[i], bf[j], acc[i][j], 0, 0, 0);
    __builtin_amdgcn_s_setprio(0);
    asm volatile("s_barrier" ::: "memory");

    // ---- phase 1: kk0, i-half 1 (reuse B) ----
#pragma unroll
    for (int i = 0; i < 4; i++)
      af[i] = *(const short8*)(la0 + (wm + 64 + i * 16 + fr) * 32 + kh);
    if (more) STG(gB, nb0, kt + 1, 0);
    asm volatile("s_barrier" ::: "memory");
    asm volatile("s_waitcnt lgkmcnt(0)" ::: "memory");
    __builtin_amdgcn_s_setprio(1);
#pragma unroll
    for (int i = 0; i < 4; i++)
#pragma unroll
      for (int j = 0; j < 4; j++)
        acc[i + 4][j] = __builtin_amdgcn_mfma_f32_16x16x32_bf16(af[i], bf[j], acc[i + 4][j], 0, 0, 0);
    __builtin_amdgcn_s_setprio(0);
    if (more) { asm volatile("s_waitcnt vmcnt(4)" ::: "memory"); }
    else      { asm volatile("s_waitcnt vmcnt(0)" ::: "memory"); }
    asm volatile("s_barrier" ::: "memory");

    // ---- phase 2: kk1, i-half 0 (+ B kk1 frags) ----
#pragma unroll
    for (int i = 0; i < 4; i++)
      af[i] = *(const short8*)(la1 + (wm + i * 16 + fr) * 32 + kh);
#pragma unroll
    for (int j = 0; j < 4; j++)
      bf[j] = *(const short8*)(lb1 + (wn + j * 16 + fr) * 32 + kh);
    if (more) STG(gA, na1, kt + 1, 1);
    asm volatile("s_barrier" ::: "memory");
    asm volatile("s_waitcnt lgkmcnt(0)" ::: "memory");
    __builtin_amdgcn_s_setprio(1);
#pragma unroll
    for (int i = 0; i < 4; i++)
#pragma unroll
      for (int j = 0; j < 4; j++)
        acc[i][j] = __builtin_amdgcn_mfma_f32_16x16x32_bf16(af[i], bf[j], acc[i][j], 0, 0, 0);
    __builtin_amdgcn_s_setprio(0);
    asm volatile("s_barrier" ::: "memory");

    // ---- phase 3: kk1, i-half 1 ----
#pragma unroll
    for (int i = 0; i < 4; i++)
      af[i] = *(const short8*)(la1 + (wm + 64 + i * 16 + fr) * 32 + kh);
    if (more) STG(gB, nb1, kt + 1, 1);
    asm volatile("s_barrier" ::: "memory");
    asm volatile("s_waitcnt lgkmcnt(0)" ::: "memory");
    __builtin_amdgcn_s_setprio(1);
#pragma unroll
    for (int i = 0; i < 4; i++)
#pragma unroll
      for (int j = 0; j < 4; j++)
        acc[i + 4][j] = __builtin_amdgcn_mfma_f32_16x16x32_bf16(af[i], bf[j], acc[i + 4][j], 0, 0, 0);
    __builtin_amdgcn_s_setprio(0);
    if (more) { asm volatile("s_waitcnt vmcnt(4)" ::: "memory"); }
    asm volatile("s_barrier" ::: "memory");
  }

  // ---- epilogue: C store + fused exp-sum partials ----
  float rs[32];
#pragma unroll
  for (int q = 0; q < 32; q++) rs[q] = 0.0f;
#pragma unroll
  for (int i = 0; i < 8; i++)
#pragma unroll
    for (int j = 0; j < 4; j++) {
      int col = bcol + wn + j * 16 + fr;
      if (col < VOCAB) {
#pragma unroll
        for (int r = 0; r < 4; r++) {
          int row = brow + wm + i * 16 + fq * 4 + r;
          float val = acc[i][j][r];
          C[(size_t)row * VOCAB + col] = val;
          rs[i * 4 + r] += __expf(val - 20.0f);
        }
      }
    }
#pragma unroll
  for (int q = 0; q < 32; q++) {
    float s = rs[q];
    s += __shfl_xor(s, 1); s += __shfl_xor(s, 2);
    s += __shfl_xor(s, 4); s += __shfl_xor(s, 8);
    rs[q] = s;
  }
  if (fr == 0) {
    int pc = ct * 4 + (wid & 3);
#pragma unroll
    for (int i = 0; i < 8; i++)
#pragma unroll
      for (int r = 0; r < 4; r++) {
        int row = brow + wm + i * 16 + fq * 4 + r;
        part[(size_t)pc * LSEQ + row] = rs[i * 4 + r];
      }
  }
}

// ---------------- causal conv1d (K=4) + silu -> bf16, vectorized x8 ----------
__global__ void k_conv_silu(const u16* __restrict__ xzb, const float* __restrict__ cw,
                            const float* __restrict__ cb, u16* __restrict__ xib) {
  int i = blockIdx.x * 256 + threadIdx.x;      // L * D_INNER/8 threads
  int t = i / (D_INNER / 8), d8 = (i % (D_INNER / 8)) * 8;
  float acc[8];
#pragma unroll
  for (int q = 0; q < 8; q++) acc[q] = cb[d8 + q];
#pragma unroll
  for (int k = 0; k < 4; k++) {
    int tt = t - 3 + k;
    if (tt >= 0) {
      short8 v = *(const short8*)(xzb + (long)tt * (2 * D_INNER) + d8);
#pragma unroll
      for (int q = 0; q < 8; q++) acc[q] += bf2f((u16)v[q]) * cw[(d8 + q) * 4 + k];
    }
  }
  short8 o;
#pragma unroll
  for (int q = 0; q < 8; q++) {
    float s = acc[q] / (1.0f + __expf(-acc[q]));
    o[q] = (short)f2bf(s);
  }
  *(short8*)(xib + (long)t * D_INNER + d8) = o;
}

// ---------------- reduce x_proj partials (16) -> xdbl + dt-pad bf16 ----------
__global__ void k_red_xd(const float* __restrict__ pxp, float* __restrict__ xdbl,
                         u16* __restrict__ dtp) {
  int i = blockIdx.x * 256 + threadIdx.x;
  int t = i >> 7, k = i & 127;
  if (k < 80) {
    float s = 0.0f;
#pragma unroll
    for (int p = 0; p < 16; p++) s += pxp[(size_t)p * LSEQ * 80 + (long)t * 80 + k];
    xdbl[(long)t * 80 + k] = s;
    if (k < DT_RANK) dtp[(long)t * 64 + k] = f2bf(s);
    else if (k < 64) dtp[(long)t * 64 + k] = 0;
  }
}

// ---------------- selective scan: 3-phase chunked (dt is bf16) ---------------
__global__ void k_scanA(const u16* __restrict__ dt, const u16* __restrict__ xi,
                        const float* __restrict__ xdbl, const float* __restrict__ a_log,
                        float* __restrict__ aprod, float* __restrict__ hend) {
  int d = blockIdx.x * 256 + threadIdx.x;
  int c = blockIdx.y;
  float A[16], ap[16], h[16];
#pragma unroll
  for (int s = 0; s < 16; s++) { A[s] = -__expf(a_log[d * 16 + s]); ap[s] = 1.0f; h[s] = 0.0f; }
  int t0 = c * TCHUNK;
  for (int t = t0; t < t0 + TCHUNK; t++) {
    float dtv = bf2f(dt[(long)t * D_INNER + d]), xv = bf2f(xi[(long)t * D_INNER + d]);
    float dx = dtv * xv;
    const float* Bp = xdbl + (long)t * 80 + DT_RANK;
#pragma unroll
    for (int s = 0; s < 16; s++) {
      float a = __expf(dtv * A[s]);
      h[s] = a * h[s] + dx * Bp[s];
      ap[s] *= a;
    }
  }
  long base = ((long)c * D_INNER + d) * 16;
#pragma unroll
  for (int s = 0; s < 16; s++) { aprod[base + s] = ap[s]; hend[base + s] = h[s]; }
}

__global__ void k_scanB(const float* __restrict__ aprod, const float* __restrict__ hend,
                        float* __restrict__ hinit) {
  int i = blockIdx.x * 256 + threadIdx.x;
  float h = 0.0f;
  for (int c = 0; c < NCHUNK; c++) {
    long idx = (long)c * D_INNER * 16 + i;
    hinit[idx] = h;
    h = aprod[idx] * h + hend[idx];
  }
}

__global__ void k_scanC(const u16* __restrict__ dt, const u16* __restrict__ xi,
                        const float* __restrict__ xdbl, const float* __restrict__ a_log,
                        const float* __restrict__ hinit, const float* __restrict__ Dp,
                        const u16* __restrict__ xzb, u16* __restrict__ yb) {
  int d = blockIdx.x * 256 + threadIdx.x;
  int c = blockIdx.y;
  float A[16], h[16];
  long hb = (long)c * D_INNER * 16 + (long)d * 16;
#pragma unroll
  for (int s = 0; s < 16; s++) { A[s] = -__expf(a_log[d * 16 + s]); h[s] = hinit[hb + s]; }
  float Dv = Dp[d];
  int t0 = c * TCHUNK;
  for (int t = t0; t < t0 + TCHUNK; t++) {
    float dtv = bf2f(dt[(long)t * D_INNER + d]), xv = bf2f(xi[(long)t * D_INNER + d]);
    float dx = dtv * xv;
    const float* Bp = xdbl + (long)t * 80 + DT_RANK;
    const float* Cp = Bp + D_STATE;
    float o = xv * Dv;
#pragma unroll
    for (int s = 0; s < 16; s++) {
      float a = __expf(dtv * A[s]);
      h[s] = a * h[s] + dx * Bp[s];
      o += h[s] * Cp[s];
    }
    float z = bf2f(xzb[(long)t * (2 * D_INNER) + D_INNER + d]);
    yb[(long)t * D_INNER + d] = f2bf(o * (z / (1.0f + __expf(-z))));
  }
}

// ---------------- final lse from partials + nll ------------------------------
__global__ void k_lse_final(const float* __restrict__ part, const float* __restrict__ logits,
                            const int* __restrict__ tgt, float* __restrict__ nll,
                            float* __restrict__ msk) {
  int t = blockIdx.x * 256 + threadIdx.x;
  float s = 0.0f;
  for (int p = 0; p < 800; p++) s += part[(size_t)p * LSEQ + t];
  float lse = 20.0f + __logf(s);
  int tg = tgt[t];
  float mk = tg >= 0 ? 1.0f : 0.0f;
  int tc = tg < 0 ? 0 : (tg > VOCAB - 1 ? VOCAB - 1 : tg);
  nll[t] = (lse - logits[(size_t)t * VOCAB + tc]) * mk;
  msk[t] = mk;
}

__global__ void k_loss(const float* __restrict__ nll, const float* __restrict__ msk,
                       float* __restrict__ out) {
  int tid = threadIdx.x;
  __shared__ float r1[256], r2[256];
  float a = 0.0f, b = 0.0f;
  for (int i = tid; i < LSEQ; i += 256) { a += nll[i]; b += msk[i]; }
  r1[tid] = a; r2[tid] = b; __syncthreads();
  for (int o = 128; o > 0; o >>= 1) {
    if (tid < o) { r1[tid] += r1[tid + o]; r2[tid] += r2[tid + o]; }
    __syncthreads();
  }
  if (tid == 0) out[0] = r1[0] / fmaxf(r2[0], 1.0f);
}

// =============================================================================
extern "C" void kernel_launch(void* const* d_in, const int* in_sizes, int n_in,
                              void* d_out, int out_size, void* d_ws, size_t ws_size,
                              hipStream_t stream) {
  const int*   idx    = (const int*)d_in[0];
  const int*   tgt    = (const int*)d_in[1];
  const float* emb    = (const float*)d_in[2];
  const float* norm_w = (const float*)d_in[3];
  const float* in_w   = (const float*)d_in[4];
  const float* conv_w = (const float*)d_in[5];
  const float* conv_b = (const float*)d_in[6];
  const float* xp_w   = (const float*)d_in[7];
  const float* dt_w   = (const float*)d_in[8];
  const float* dt_b   = (const float*)d_in[9];
  const float* a_log  = (const float*)d_in[10];
  const float* d_par  = (const float*)d_in[11];
  const float* out_w  = (const float*)d_in[12];
  const float* normf  = (const float*)d_in[13];

  float* logits = (float*)d_out;
  float* loss   = logits + (size_t)LSEQ * VOCAB;

  char* base = (char*)d_ws;
  size_t off = 0;
  auto alloc = [&](size_t bytes) -> char* {
    char* r = base + off;
    off = (off + bytes + 255) & ~(size_t)255;
    return r;
  };
  u16*   wcat = (u16*)  alloc((size_t)TOTCVT * 2);
  float* x    = (float*)alloc((size_t)LSEQ * D_MODEL * 4);
  u16*   xnb  = (u16*)  alloc((size_t)LSEQ * D_MODEL * 2);
  u16*   xzb  = (u16*)  alloc((size_t)LSEQ * 2 * D_INNER * 2);
  u16*   xib  = (u16*)  alloc((size_t)LSEQ * D_INNER * 2);
  float* xdbl = (float*)alloc((size_t)LSEQ * 80 * 4);
  u16*   dtp  = (u16*)  alloc((size_t)LSEQ * 64 * 2);
  u16*   dtl  = (u16*)  alloc((size_t)LSEQ * D_INNER * 2);
  u16*   yb   = (u16*)  alloc((size_t)LSEQ * D_INNER * 2);
  // shared pool: x_proj partials (16x2048x80), out_proj partials (4x2048x768),
  // lse partials (800x2048) — disjoint lifetimes.
  float* pool = (float*)alloc((size_t)4 * LSEQ * D_MODEL * 4);
  float* apr  = (float*)alloc((size_t)NCHUNK * D_INNER * 16 * 4);
  float* hen  = (float*)alloc((size_t)NCHUNK * D_INNER * 16 * 4);
  float* hin  = (float*)alloc((size_t)NCHUNK * D_INNER * 16 * 4);
  float* nll  = (float*)alloc((size_t)LSEQ * 4);
  float* msk  = (float*)alloc((size_t)LSEQ * 4);
  float* pxp  = pool;
  float* pop  = pool;
  float* part = pool;
  (void)ws_size; (void)in_sizes; (void)n_in; (void)out_size;

  const u16* embb = wcat;

  k_convert_all<<<(unsigned)((TOTCVT / 4 + 255) / 256), 256, 0, stream>>>(
      emb, in_w, xp_w, dt_w, out_w, wcat);
  k_embed_rms<<<LSEQ, 256, 0, stream>>>(idx, emb, norm_w, x, xnb);

  for (int l = 0; l < N_LAYER; l++) {
    const u16* w1 = wcat + EMB_E + (long)l * PERL;
    const u16* w2 = w1 + W1E;
    const u16* w3 = w2 + W2E;
    const u16* w4 = w3 + W3E;

    k_gemm2<2><<<dim3(24, 16), 256, 0, stream>>>(
        xnb, w1, xzb, nullptr, 2 * D_INNER, D_MODEL, D_MODEL, D_MODEL, 2 * D_INNER);

    k_conv_silu<<<(LSEQ * D_INNER / 8) / 256, 256, 0, stream>>>(
        xzb, conv_w + (long)l * D_INNER * 4, conv_b + l * D_INNER, xib);

    k_gemm_part<<<dim3(1, 16, 16), 256, 0, stream>>>(
        xib, w2, pxp, 80, D_INNER / 16, D_INNER, D_INNER, 80);
    k_red_xd<<<(LSEQ * 128) / 256, 256, 0, stream>>>(pxp, xdbl, dtp);

    k_gemm2<1><<<dim3(12, 16), 256, 0, stream>>>(
        dtp, w3, dtl, dt_b + l * D_INNER, D_INNER, 64, 64, 64, D_INNER);

    const float* al = a_log + (long)l * D_INNER * D_STATE;
    k_scanA<<<dim3(D_INNER / 256, NCHUNK), 256, 0, stream>>>(dtl, xib, xdbl, al, apr, hen);
    k_scanB<<<(D_INNER * 16) / 256, 256, 0, stream>>>(apr, hen, hin);
    k_scanC<<<dim3(D_INNER / 256, NCHUNK), 256, 0, stream>>>(
        dtl, xib, xdbl, al, hin, d_par + l * D_INNER, xzb, yb);

    k_gemm_part<<<dim3(6, 16, 4), 256, 0, stream>>>(
        yb, w4, pop, D_MODEL, D_INNER / 4, D_INNER, D_INNER, D_MODEL);

    const float* wn = (l < N_LAYER - 1) ? (norm_w + (l + 1) * D_MODEL) : normf;
    k_rms_red<<<LSEQ, 256, 0, stream>>>(pop, wn, x, xnb);
  }

  k_gemm_logits8<<<1600, 512, 0, stream>>>(xnb, embb, logits, part);
  k_lse_final<<<LSEQ / 256, 256, 0, stream>>>(part, logits, tgt, nll, msk);
  k_loss<<<1, 256, 0, stream>>>(nll, msk, loss);
}

// Round 12
// 1136.855 us; speedup vs baseline: 1.0496x; 1.0496x over previous
//
#include <hip/hip_runtime.h>
#include <stdint.h>

// Mamba forward, MI355X. Round 12 (revert to measured best = round 10).
//  - logits: 2-phase 256x128 tile, depth-2 counted vmcnt(6), (256,2),
//    T2 swizzle (bank conflicts 0), XCD-bijective walk, fused LSE partials.
//    Ledger: d2=257/259 BEST, d3=266, 128sq@occ3=300, 8-phase-1blk=310,
//    (256,3)+AGPR-spill=724+.
//  - layers: PIPELINE3, split-K16 x_proj, dt-GEMM bf16 out, vectorized conv.

#define D_MODEL 768
#define N_LAYER 4
#define VOCAB 50257
#define D_STATE 16
#define D_INNER 1536
#define DT_RANK 48
#define LSEQ 2048
#define TCHUNK 64
#define NCHUNK 32

#define EMB_E 39321600L            // 51200*768
#define W1E 2359296L               // 3072*768
#define W2E 196608L                // 128*1536
#define W3E 98304L                 // 1536*64
#define W4E 1179648L               // 768*1536
#define PERL (W1E + W2E + W3E + W4E)
#define TOTCVT (EMB_E + 4 * PERL)

typedef unsigned short u16;
typedef __attribute__((ext_vector_type(8))) short short8;
typedef __attribute__((ext_vector_type(4))) float f32x4;
typedef __attribute__((ext_vector_type(4))) unsigned short us4;

__device__ __forceinline__ u16 f2bf(float f) {
  unsigned int x = __float_as_uint(f);
  x += 0x7fffu + ((x >> 16) & 1u);   // RNE
  return (u16)(x >> 16);
}
__device__ __forceinline__ float bf2f(u16 v) {
  return __uint_as_float(((unsigned int)v) << 16);
}
__device__ __forceinline__ void gl16(const void* g, void* l) {
  __builtin_amdgcn_global_load_lds((const __attribute__((address_space(1))) void*)g,
                                   (__attribute__((address_space(3))) void*)l, 16, 0, 0);
}

// 3-deep counted-vmcnt K-loop (128x128 tile kernels; 4 loads/stage).
#define PIPELINE3(NT)                                                         \
  STAGE(0, 0);                                                                \
  if ((NT) > 1) STAGE(32, 1);                                                 \
  if ((NT) > 2) STAGE(64, 2);                                                 \
  {                                                                           \
    int cur = 0;                                                              \
    for (int t = 0; t < (NT); t++) {                                          \
      int rem = (NT) - 1 - t;                                                 \
      if (rem >= 2)      { asm volatile("s_waitcnt vmcnt(8)" ::: "memory"); } \
      else if (rem == 1) { asm volatile("s_waitcnt vmcnt(4)" ::: "memory"); } \
      else               { asm volatile("s_waitcnt vmcnt(0)" ::: "memory"); } \
      asm volatile("s_barrier" ::: "memory");                                 \
      short8 af[4], bfr[4];                                                   \
      _Pragma("unroll")                                                       \
      for (int i = 0; i < 4; i++)                                             \
        af[i] = *(const short8*)(&lA[cur][(wm + i * 16 + fr) * 32 + kh]);     \
      _Pragma("unroll")                                                       \
      for (int j = 0; j < 4; j++)                                             \
        bfr[j] = *(const short8*)(&lB[cur][(wn + j * 16 + fr) * 32 + kh]);    \
      asm volatile("s_waitcnt lgkmcnt(0)" ::: "memory");                      \
      asm volatile("s_barrier" ::: "memory");                                 \
      if (t + 3 < (NT)) STAGE((t + 3) * 32, cur);                             \
      __builtin_amdgcn_s_setprio(1);                                          \
      _Pragma("unroll")                                                       \
      for (int i = 0; i < 4; i++)                                             \
        _Pragma("unroll")                                                     \
        for (int j = 0; j < 4; j++)                                           \
          acc[i][j] = __builtin_amdgcn_mfma_f32_16x16x32_bf16(af[i], bfr[j],  \
                                                              acc[i][j], 0, 0, 0); \
      __builtin_amdgcn_s_setprio(0);                                          \
      cur = (cur == 2) ? 0 : cur + 1;                                         \
    }                                                                         \
  }

// ---------------- upfront convert: emb + all layer weights -> bf16 arena -----
__global__ void k_convert_all(const float* __restrict__ emb, const float* __restrict__ in_w,
                              const float* __restrict__ xp_w, const float* __restrict__ dt_w,
                              const float* __restrict__ out_w, u16* __restrict__ dst) {
  long i0 = ((long)blockIdx.x * 256 + threadIdx.x) * 4;
  if (i0 >= TOTCVT) return;
  us4 o;
#pragma unroll
  for (int q = 0; q < 4; q++) {
    long i = i0 + q;
    float v;
    if (i < EMB_E) {
      long n = i / D_MODEL, k = i % D_MODEL;
      v = (n < VOCAB) ? emb[n * D_MODEL + k] : 0.0f;
    } else {
      long j = i - EMB_E;
      int l = (int)(j / PERL);
      long m = j % PERL;
      if (m < W1E) {
        v = in_w[(long)l * W1E + m];
      } else if (m < W1E + W2E) {
        long mm = m - W1E;
        long n = mm / D_INNER, k = mm % D_INNER;
        v = (n < 80) ? xp_w[(long)l * 80 * D_INNER + n * D_INNER + k] : 0.0f;
      } else if (m < W1E + W2E + W3E) {
        long mm = m - (W1E + W2E);
        long n = mm / 64, k = mm % 64;
        v = (k < DT_RANK) ? dt_w[(long)l * D_INNER * DT_RANK + n * DT_RANK + k] : 0.0f;
      } else {
        long mm = m - (W1E + W2E + W3E);
        v = out_w[(long)l * W4E + mm];
      }
    }
    o[q] = f2bf(v);
  }
  *(us4*)(dst + i0) = o;
}

// ---------------- embed + rmsnorm(layer0) ------------------------------------
__global__ void k_embed_rms(const int* __restrict__ idx, const float* __restrict__ emb,
                            const float* __restrict__ w, float* __restrict__ x,
                            u16* __restrict__ xnb) {
  int t = blockIdx.x, tid = threadIdx.x;
  __shared__ float red[256];
  const float* src = emb + (long)idx[t] * D_MODEL;
  float g[3];
  float s = 0.0f;
#pragma unroll
  for (int q = 0; q < 3; q++) {
    g[q] = src[tid + q * 256];
    s += g[q] * g[q];
  }
  red[tid] = s; __syncthreads();
  for (int o = 128; o > 0; o >>= 1) { if (tid < o) red[tid] += red[tid + o]; __syncthreads(); }
  float scale = rsqrtf(red[0] / (float)D_MODEL + 1e-5f);
#pragma unroll
  for (int q = 0; q < 3; q++) {
    int c = tid + q * 256;
    x[(long)t * D_MODEL + c] = g[q];
    xnb[(long)t * D_MODEL + c] = f2bf(g[q] * scale * w[c]);
  }
}

// ---------------- reduce out_proj partials + residual + rmsnorm --------------
__global__ void k_rms_red(const float* __restrict__ part, const float* __restrict__ w,
                          float* __restrict__ x, u16* __restrict__ xnb) {
  int t = blockIdx.x, tid = threadIdx.x;
  __shared__ float red[256];
  float g[3];
  float s = 0.0f;
#pragma unroll
  for (int q = 0; q < 3; q++) {
    int c = tid + q * 256;
    long off = (long)t * D_MODEL + c;
    float v = x[off];
#pragma unroll
    for (int p = 0; p < 4; p++) v += part[(size_t)p * LSEQ * D_MODEL + off];
    g[q] = v;
    s += v * v;
  }
  red[tid] = s; __syncthreads();
  for (int o = 128; o > 0; o >>= 1) { if (tid < o) red[tid] += red[tid + o]; __syncthreads(); }
  float scale = rsqrtf(red[0] / (float)D_MODEL + 1e-5f);
#pragma unroll
  for (int q = 0; q < 3; q++) {
    int c = tid + q * 256;
    x[(long)t * D_MODEL + c] = g[q];
    xnb[(long)t * D_MODEL + c] = f2bf(g[q] * scale * w[c]);
  }
}

// ---------------- 128x128 3-deep GEMM: C = A(M,K) * W(N,K)^T -----------------
// EPI: 1 = softplus(acc+bias[col]) -> bf16, 2 = bf16 store
template<int EPI>
__global__ __launch_bounds__(256) void k_gemm2(
    const u16* __restrict__ A, const u16* __restrict__ W, void* __restrict__ Cv,
    const float* __restrict__ bias, int N, int K, int lda, int ldb, int ldc) {
  __shared__ u16 lA[3][128 * 32];
  __shared__ u16 lB[3][128 * 32];
  const int gx = gridDim.x, gy = gridDim.y;
  int id = blockIdx.x + gx * blockIdx.y;
  int q8 = (gx * gy) >> 3;
  int v = (id & 7) * q8 + (id >> 3);
  const int bx = v / gy, by = v % gy;
  const int brow = by * 128, bcol = bx * 128;
  const int tid = threadIdx.x, wid = tid >> 6, lane = tid & 63;
  const int wm = (wid >> 1) * 64, wn = (wid & 1) * 64;
  const int fr = lane & 15, fq = lane >> 4;
  const int kh = 8 * (fq ^ ((fr >> 1) & 3));                    // swizzled read slot
  const int srow = tid >> 2;
  const int lcol = (tid & 3) * 8;                               // linear LDS col
  const int scol = 8 * ((tid & 3) ^ ((srow >> 1) & 3));         // swizzled source col
  const u16* ga0 = A + (size_t)(brow + srow) * lda + scol;
  const u16* ga1 = A + (size_t)(brow + srow + 64) * lda + scol;
  const u16* gb0 = W + (size_t)(bcol + srow) * ldb + scol;
  const u16* gb1 = W + (size_t)(bcol + srow + 64) * ldb + scol;
  const int lo = srow * 32 + lcol;

  f32x4 acc[4][4];
#pragma unroll
  for (int i = 0; i < 4; i++)
#pragma unroll
    for (int j = 0; j < 4; j++)
#pragma unroll
      for (int r = 0; r < 4; r++) acc[i][j][r] = 0.0f;

  auto STAGE = [&](int k0, int b) {
    gl16(ga0 + k0, &lA[b][lo]);
    gl16(ga1 + k0, &lA[b][lo + 2048]);
    gl16(gb0 + k0, &lB[b][lo]);
    gl16(gb1 + k0, &lB[b][lo + 2048]);
  };

  PIPELINE3(K / 32);

#pragma unroll
  for (int i = 0; i < 4; i++)
#pragma unroll
    for (int j = 0; j < 4; j++) {
      int col = bcol + wn + j * 16 + fr;
      if (col < N) {
#pragma unroll
        for (int r = 0; r < 4; r++) {
          int row = brow + wm + i * 16 + fq * 4 + r;
          float val = acc[i][j][r];
          if (EPI == 1) {
            val += bias[col];
            val = (val > 20.0f) ? val : log1pf(__expf(val));
            ((u16*)Cv)[(size_t)row * ldc + col] = f2bf(val);
          } else {
            ((u16*)Cv)[(size_t)row * ldc + col] = f2bf(val);
          }
        }
      }
    }
}

// ---------------- split-K partial GEMM (3-deep) ------------------------------
__global__ __launch_bounds__(256) void k_gemm_part(
    const u16* __restrict__ A, const u16* __restrict__ W, float* __restrict__ Cp,
    int N, int Ks, int lda, int ldb, int ldc) {
  __shared__ u16 lA[3][128 * 32];
  __shared__ u16 lB[3][128 * 32];
  const int gx = gridDim.x, gy = gridDim.y;
  int id = blockIdx.x + gx * blockIdx.y;
  int q8 = (gx * gy) >> 3;
  int v = (id & 7) * q8 + (id >> 3);
  const int bx = v / gy, by = v % gy;
  const int brow = by * 128, bcol = bx * 128;
  const int koff = blockIdx.z * Ks;
  const int tid = threadIdx.x, wid = tid >> 6, lane = tid & 63;
  const int wm = (wid >> 1) * 64, wn = (wid & 1) * 64;
  const int fr = lane & 15, fq = lane >> 4;
  const int kh = 8 * (fq ^ ((fr >> 1) & 3));
  const int srow = tid >> 2;
  const int lcol = (tid & 3) * 8;
  const int scol = 8 * ((tid & 3) ^ ((srow >> 1) & 3));
  const u16* ga0 = A + (size_t)(brow + srow) * lda + koff + scol;
  const u16* ga1 = A + (size_t)(brow + srow + 64) * lda + koff + scol;
  const u16* gb0 = W + (size_t)(bcol + srow) * ldb + koff + scol;
  const u16* gb1 = W + (size_t)(bcol + srow + 64) * ldb + koff + scol;
  const int lo = srow * 32 + lcol;

  f32x4 acc[4][4];
#pragma unroll
  for (int i = 0; i < 4; i++)
#pragma unroll
    for (int j = 0; j < 4; j++)
#pragma unroll
      for (int r = 0; r < 4; r++) acc[i][j][r] = 0.0f;

  auto STAGE = [&](int k0, int b) {
    gl16(ga0 + k0, &lA[b][lo]);
    gl16(ga1 + k0, &lA[b][lo + 2048]);
    gl16(gb0 + k0, &lB[b][lo]);
    gl16(gb1 + k0, &lB[b][lo + 2048]);
  };

  PIPELINE3(Ks / 32);

  float* Cz = Cp + (size_t)blockIdx.z * LSEQ * ldc;
#pragma unroll
  for (int i = 0; i < 4; i++)
#pragma unroll
    for (int j = 0; j < 4; j++) {
      int col = bcol + wn + j * 16 + fr;
      if (col < N) {
#pragma unroll
        for (int r = 0; r < 4; r++) {
          int row = brow + wm + i * 16 + fq * 4 + r;
          Cz[(size_t)row * ldc + col] = acc[i][j][r];
        }
      }
    }
}

// ---------------- logits GEMM: 256x128 tile, per-wave 128x64, depth-2 --------
// Best measured config (257-259us). launch_bounds(256,2): acc[8][4] =
// 128 AGPR + ~100 VGPR = 228 regs <= 256 at 2 waves/SIMD; 3 would spill.
__global__ __launch_bounds__(256, 2) void k_gemm_logits(
    const u16* __restrict__ A, const u16* __restrict__ W, float* __restrict__ C,
    float* __restrict__ part) {
  __shared__ u16 lA[2][256 * 32];
  __shared__ u16 lB[2][128 * 32];
  const int b = blockIdx.x;
  const int xcd = b & 7, slot = b >> 3;
  const int ct = xcd * 50 + (slot >> 3), rt = slot & 7;
  const int brow = rt * 256, bcol = ct * 128;
  const int tid = threadIdx.x, wid = tid >> 6, lane = tid & 63;
  const int wm = (wid >> 1) * 128, wn = (wid & 1) * 64;
  const int fr = lane & 15, fq = lane >> 4;
  const int kh = 8 * (fq ^ ((fr >> 1) & 3));
  const int srow = tid >> 2;
  const int lcol = (tid & 3) * 8;
  const int scol = 8 * ((tid & 3) ^ ((srow >> 1) & 3));
  const u16* ga = A + (size_t)(brow + srow) * D_MODEL + scol;
  const u16* gb = W + (size_t)(bcol + srow) * D_MODEL + scol;
  const int lo = srow * 32 + lcol;

  f32x4 acc[8][4];
#pragma unroll
  for (int i = 0; i < 8; i++)
#pragma unroll
    for (int j = 0; j < 4; j++)
#pragma unroll
      for (int r = 0; r < 4; r++) acc[i][j][r] = 0.0f;

  auto STAGE = [&](int k0, int bb) {
    gl16(ga + k0, &lA[bb][lo]);
    gl16(ga + (size_t)64 * D_MODEL + k0, &lA[bb][lo + 2048]);
    gl16(ga + (size_t)128 * D_MODEL + k0, &lA[bb][lo + 4096]);
    gl16(ga + (size_t)192 * D_MODEL + k0, &lA[bb][lo + 6144]);
    gl16(gb + k0, &lB[bb][lo]);
    gl16(gb + (size_t)64 * D_MODEL + k0, &lB[bb][lo + 2048]);
  };

  STAGE(0, 0);
  STAGE(32, 1);
  int cur = 0;
  const int NT = D_MODEL / 32;
  for (int t = 0; t < NT; t++) {
    if (t + 1 < NT) { asm volatile("s_waitcnt vmcnt(6)" ::: "memory"); }
    else            { asm volatile("s_waitcnt vmcnt(0)" ::: "memory"); }
    asm volatile("s_barrier" ::: "memory");
    short8 af[8], bfr[4];
#pragma unroll
    for (int i = 0; i < 8; i++)
      af[i] = *(const short8*)(&lA[cur][(wm + i * 16 + fr) * 32 + kh]);
#pragma unroll
    for (int j = 0; j < 4; j++)
      bfr[j] = *(const short8*)(&lB[cur][(wn + j * 16 + fr) * 32 + kh]);
    asm volatile("s_waitcnt lgkmcnt(0)" ::: "memory");
    asm volatile("s_barrier" ::: "memory");
    if (t + 2 < NT) STAGE((t + 2) * 32, cur);
    __builtin_amdgcn_s_setprio(1);
#pragma unroll
    for (int i = 0; i < 8; i++)
#pragma unroll
      for (int j = 0; j < 4; j++)
        acc[i][j] = __builtin_amdgcn_mfma_f32_16x16x32_bf16(af[i], bfr[j], acc[i][j], 0, 0, 0);
    __builtin_amdgcn_s_setprio(0);
    cur ^= 1;
  }

  float rs[32];
#pragma unroll
  for (int q = 0; q < 32; q++) rs[q] = 0.0f;
#pragma unroll
  for (int i = 0; i < 8; i++)
#pragma unroll
    for (int j = 0; j < 4; j++) {
      int col = bcol + wn + j * 16 + fr;
      if (col < VOCAB) {
#pragma unroll
        for (int r = 0; r < 4; r++) {
          int row = brow + wm + i * 16 + fq * 4 + r;
          float val = acc[i][j][r];
          C[(size_t)row * VOCAB + col] = val;
          rs[i * 4 + r] += __expf(val - 20.0f);
        }
      }
    }
#pragma unroll
  for (int q = 0; q < 32; q++) {
    float s = rs[q];
    s += __shfl_xor(s, 1); s += __shfl_xor(s, 2);
    s += __shfl_xor(s, 4); s += __shfl_xor(s, 8);
    rs[q] = s;
  }
  if (fr == 0) {
    int pc = ct * 2 + (wn >> 6);
#pragma unroll
    for (int i = 0; i < 8; i++)
#pragma unroll
      for (int r = 0; r < 4; r++) {
        int row = brow + wm + i * 16 + fq * 4 + r;
        part[(size_t)pc * LSEQ + row] = rs[i * 4 + r];
      }
  }
}

// ---------------- causal conv1d (K=4) + silu -> bf16, vectorized x8 ----------
__global__ void k_conv_silu(const u16* __restrict__ xzb, const float* __restrict__ cw,
                            const float* __restrict__ cb, u16* __restrict__ xib) {
  int i = blockIdx.x * 256 + threadIdx.x;      // L * D_INNER/8 threads
  int t = i / (D_INNER / 8), d8 = (i % (D_INNER / 8)) * 8;
  float acc[8];
#pragma unroll
  for (int q = 0; q < 8; q++) acc[q] = cb[d8 + q];
#pragma unroll
  for (int k = 0; k < 4; k++) {
    int tt = t - 3 + k;
    if (tt >= 0) {
      short8 v = *(const short8*)(xzb + (long)tt * (2 * D_INNER) + d8);
#pragma unroll
      for (int q = 0; q < 8; q++) acc[q] += bf2f((u16)v[q]) * cw[(d8 + q) * 4 + k];
    }
  }
  short8 o;
#pragma unroll
  for (int q = 0; q < 8; q++) {
    float s = acc[q] / (1.0f + __expf(-acc[q]));
    o[q] = (short)f2bf(s);
  }
  *(short8*)(xib + (long)t * D_INNER + d8) = o;
}

// ---------------- reduce x_proj partials (16) -> xdbl + dt-pad bf16 ----------
__global__ void k_red_xd(const float* __restrict__ pxp, float* __restrict__ xdbl,
                         u16* __restrict__ dtp) {
  int i = blockIdx.x * 256 + threadIdx.x;
  int t = i >> 7, k = i & 127;
  if (k < 80) {
    float s = 0.0f;
#pragma unroll
    for (int p = 0; p < 16; p++) s += pxp[(size_t)p * LSEQ * 80 + (long)t * 80 + k];
    xdbl[(long)t * 80 + k] = s;
    if (k < DT_RANK) dtp[(long)t * 64 + k] = f2bf(s);
    else if (k < 64) dtp[(long)t * 64 + k] = 0;
  }
}

// ---------------- selective scan: 3-phase chunked (dt is bf16) ---------------
__global__ void k_scanA(const u16* __restrict__ dt, const u16* __restrict__ xi,
                        const float* __restrict__ xdbl, const float* __restrict__ a_log,
                        float* __restrict__ aprod, float* __restrict__ hend) {
  int d = blockIdx.x * 256 + threadIdx.x;
  int c = blockIdx.y;
  float A[16], ap[16], h[16];
#pragma unroll
  for (int s = 0; s < 16; s++) { A[s] = -__expf(a_log[d * 16 + s]); ap[s] = 1.0f; h[s] = 0.0f; }
  int t0 = c * TCHUNK;
  for (int t = t0; t < t0 + TCHUNK; t++) {
    float dtv = bf2f(dt[(long)t * D_INNER + d]), xv = bf2f(xi[(long)t * D_INNER + d]);
    float dx = dtv * xv;
    const float* Bp = xdbl + (long)t * 80 + DT_RANK;
#pragma unroll
    for (int s = 0; s < 16; s++) {
      float a = __expf(dtv * A[s]);
      h[s] = a * h[s] + dx * Bp[s];
      ap[s] *= a;
    }
  }
  long base = ((long)c * D_INNER + d) * 16;
#pragma unroll
  for (int s = 0; s < 16; s++) { aprod[base + s] = ap[s]; hend[base + s] = h[s]; }
}

__global__ void k_scanB(const float* __restrict__ aprod, const float* __restrict__ hend,
                        float* __restrict__ hinit) {
  int i = blockIdx.x * 256 + threadIdx.x;
  float h = 0.0f;
  for (int c = 0; c < NCHUNK; c++) {
    long idx = (long)c * D_INNER * 16 + i;
    hinit[idx] = h;
    h = aprod[idx] * h + hend[idx];
  }
}

__global__ void k_scanC(const u16* __restrict__ dt, const u16* __restrict__ xi,
                        const float* __restrict__ xdbl, const float* __restrict__ a_log,
                        const float* __restrict__ hinit, const float* __restrict__ Dp,
                        const u16* __restrict__ xzb, u16* __restrict__ yb) {
  int d = blockIdx.x * 256 + threadIdx.x;
  int c = blockIdx.y;
  float A[16], h[16];
  long hb = (long)c * D_INNER * 16 + (long)d * 16;
#pragma unroll
  for (int s = 0; s < 16; s++) { A[s] = -__expf(a_log[d * 16 + s]); h[s] = hinit[hb + s]; }
  float Dv = Dp[d];
  int t0 = c * TCHUNK;
  for (int t = t0; t < t0 + TCHUNK; t++) {
    float dtv = bf2f(dt[(long)t * D_INNER + d]), xv = bf2f(xi[(long)t * D_INNER + d]);
    float dx = dtv * xv;
    const float* Bp = xdbl + (long)t * 80 + DT_RANK;
    const float* Cp = Bp + D_STATE;
    float o = xv * Dv;
#pragma unroll
    for (int s = 0; s < 16; s++) {
      float a = __expf(dtv * A[s]);
      h[s] = a * h[s] + dx * Bp[s];
      o += h[s] * Cp[s];
    }
    float z = bf2f(xzb[(long)t * (2 * D_INNER) + D_INNER + d]);
    yb[(long)t * D_INNER + d] = f2bf(o * (z / (1.0f + __expf(-z))));
  }
}

// ---------------- final lse from partials + nll ------------------------------
__global__ void k_lse_final(const float* __restrict__ part, const float* __restrict__ logits,
                            const int* __restrict__ tgt, float* __restrict__ nll,
                            float* __restrict__ msk) {
  int t = blockIdx.x * 256 + threadIdx.x;
  float s = 0.0f;
  for (int p = 0; p < 800; p++) s += part[(size_t)p * LSEQ + t];
  float lse = 20.0f + __logf(s);
  int tg = tgt[t];
  float mk = tg >= 0 ? 1.0f : 0.0f;
  int tc = tg < 0 ? 0 : (tg > VOCAB - 1 ? VOCAB - 1 : tg);
  nll[t] = (lse - logits[(size_t)t * VOCAB + tc]) * mk;
  msk[t] = mk;
}

__global__ void k_loss(const float* __restrict__ nll, const float* __restrict__ msk,
                       float* __restrict__ out) {
  int tid = threadIdx.x;
  __shared__ float r1[256], r2[256];
  float a = 0.0f, b = 0.0f;
  for (int i = tid; i < LSEQ; i += 256) { a += nll[i]; b += msk[i]; }
  r1[tid] = a; r2[tid] = b; __syncthreads();
  for (int o = 128; o > 0; o >>= 1) {
    if (tid < o) { r1[tid] += r1[tid + o]; r2[tid] += r2[tid + o]; }
    __syncthreads();
  }
  if (tid == 0) out[0] = r1[0] / fmaxf(r2[0], 1.0f);
}

// =============================================================================
extern "C" void kernel_launch(void* const* d_in, const int* in_sizes, int n_in,
                              void* d_out, int out_size, void* d_ws, size_t ws_size,
                              hipStream_t stream) {
  const int*   idx    = (const int*)d_in[0];
  const int*   tgt    = (const int*)d_in[1];
  const float* emb    = (const float*)d_in[2];
  const float* norm_w = (const float*)d_in[3];
  const float* in_w   = (const float*)d_in[4];
  const float* conv_w = (const float*)d_in[5];
  const float* conv_b = (const float*)d_in[6];
  const float* xp_w   = (const float*)d_in[7];
  const float* dt_w   = (const float*)d_in[8];
  const float* dt_b   = (const float*)d_in[9];
  const float* a_log  = (const float*)d_in[10];
  const float* d_par  = (const float*)d_in[11];
  const float* out_w  = (const float*)d_in[12];
  const float* normf  = (const float*)d_in[13];

  float* logits = (float*)d_out;
  float* loss   = logits + (size_t)LSEQ * VOCAB;

  char* base = (char*)d_ws;
  size_t off = 0;
  auto alloc = [&](size_t bytes) -> char* {
    char* r = base + off;
    off = (off + bytes + 255) & ~(size_t)255;
    return r;
  };
  u16*   wcat = (u16*)  alloc((size_t)TOTCVT * 2);
  float* x    = (float*)alloc((size_t)LSEQ * D_MODEL * 4);
  u16*   xnb  = (u16*)  alloc((size_t)LSEQ * D_MODEL * 2);
  u16*   xzb  = (u16*)  alloc((size_t)LSEQ * 2 * D_INNER * 2);
  u16*   xib  = (u16*)  alloc((size_t)LSEQ * D_INNER * 2);
  float* xdbl = (float*)alloc((size_t)LSEQ * 80 * 4);
  u16*   dtp  = (u16*)  alloc((size_t)LSEQ * 64 * 2);
  u16*   dtl  = (u16*)  alloc((size_t)LSEQ * D_INNER * 2);
  u16*   yb   = (u16*)  alloc((size_t)LSEQ * D_INNER * 2);
  // shared pool: x_proj partials (16x2048x80), out_proj partials (4x2048x768),
  // lse partials (800x2048) — disjoint lifetimes.
  float* pool = (float*)alloc((size_t)4 * LSEQ * D_MODEL * 4);
  float* apr  = (float*)alloc((size_t)NCHUNK * D_INNER * 16 * 4);
  float* hen  = (float*)alloc((size_t)NCHUNK * D_INNER * 16 * 4);
  float* hin  = (float*)alloc((size_t)NCHUNK * D_INNER * 16 * 4);
  float* nll  = (float*)alloc((size_t)LSEQ * 4);
  float* msk  = (float*)alloc((size_t)LSEQ * 4);
  float* pxp  = pool;
  float* pop  = pool;
  float* part = pool;
  (void)ws_size; (void)in_sizes; (void)n_in; (void)out_size;

  const u16* embb = wcat;

  k_convert_all<<<(unsigned)((TOTCVT / 4 + 255) / 256), 256, 0, stream>>>(
      emb, in_w, xp_w, dt_w, out_w, wcat);
  k_embed_rms<<<LSEQ, 256, 0, stream>>>(idx, emb, norm_w, x, xnb);

  for (int l = 0; l < N_LAYER; l++) {
    const u16* w1 = wcat + EMB_E + (long)l * PERL;
    const u16* w2 = w1 + W1E;
    const u16* w3 = w2 + W2E;
    const u16* w4 = w3 + W3E;

    k_gemm2<2><<<dim3(24, 16), 256, 0, stream>>>(
        xnb, w1, xzb, nullptr, 2 * D_INNER, D_MODEL, D_MODEL, D_MODEL, 2 * D_INNER);

    k_conv_silu<<<(LSEQ * D_INNER / 8) / 256, 256, 0, stream>>>(
        xzb, conv_w + (long)l * D_INNER * 4, conv_b + l * D_INNER, xib);

    k_gemm_part<<<dim3(1, 16, 16), 256, 0, stream>>>(
        xib, w2, pxp, 80, D_INNER / 16, D_INNER, D_INNER, 80);
    k_red_xd<<<(LSEQ * 128) / 256, 256, 0, stream>>>(pxp, xdbl, dtp);

    k_gemm2<1><<<dim3(12, 16), 256, 0, stream>>>(
        dtp, w3, dtl, dt_b + l * D_INNER, D_INNER, 64, 64, 64, D_INNER);

    const float* al = a_log + (long)l * D_INNER * D_STATE;
    k_scanA<<<dim3(D_INNER / 256, NCHUNK), 256, 0, stream>>>(dtl, xib, xdbl, al, apr, hen);
    k_scanB<<<(D_INNER * 16) / 256, 256, 0, stream>>>(apr, hen, hin);
    k_scanC<<<dim3(D_INNER / 256, NCHUNK), 256, 0, stream>>>(
        dtl, xib, xdbl, al, hin, d_par + l * D_INNER, xzb, yb);

    k_gemm_part<<<dim3(6, 16, 4), 256, 0, stream>>>(
        yb, w4, pop, D_MODEL, D_INNER / 4, D_INNER, D_INNER, D_MODEL);

    const float* wn = (l < N_LAYER - 1) ? (norm_w + (l + 1) * D_MODEL) : normf;
    k_rms_red<<<LSEQ, 256, 0, stream>>>(pop, wn, x, xnb);
  }

  k_gemm_logits<<<400 * 8, 256, 0, stream>>>(xnb, embb, logits, part);
  k_lse_final<<<LSEQ / 256, 256, 0, stream>>>(part, logits, tgt, nll, msk);
  k_loss<<<1, 256, 0, stream>>>(nll, msk, loss);
}

// Round 13
// 1125.170 us; speedup vs baseline: 1.0605x; 1.0104x over previous
//
#include <hip/hip_runtime.h>
#include <stdint.h>

// Mamba forward, MI355X. Round 13:
//  - k_lse_final parallelized: was 8 blocks x 800 serial strided loads/thread
//    (248 CUs idle, ~latency-bound tail); now 1 block/token, 256 thr,
//    <=4 loads/thread + LDS tree reduce.
//  - everything else = round 12 (measured best, 1136us; logits 259us stable).

#define D_MODEL 768
#define N_LAYER 4
#define VOCAB 50257
#define D_STATE 16
#define D_INNER 1536
#define DT_RANK 48
#define LSEQ 2048
#define TCHUNK 64
#define NCHUNK 32

#define EMB_E 39321600L            // 51200*768
#define W1E 2359296L               // 3072*768
#define W2E 196608L                // 128*1536
#define W3E 98304L                 // 1536*64
#define W4E 1179648L               // 768*1536
#define PERL (W1E + W2E + W3E + W4E)
#define TOTCVT (EMB_E + 4 * PERL)

typedef unsigned short u16;
typedef __attribute__((ext_vector_type(8))) short short8;
typedef __attribute__((ext_vector_type(4))) float f32x4;
typedef __attribute__((ext_vector_type(4))) unsigned short us4;

__device__ __forceinline__ u16 f2bf(float f) {
  unsigned int x = __float_as_uint(f);
  x += 0x7fffu + ((x >> 16) & 1u);   // RNE
  return (u16)(x >> 16);
}
__device__ __forceinline__ float bf2f(u16 v) {
  return __uint_as_float(((unsigned int)v) << 16);
}
__device__ __forceinline__ void gl16(const void* g, void* l) {
  __builtin_amdgcn_global_load_lds((const __attribute__((address_space(1))) void*)g,
                                   (__attribute__((address_space(3))) void*)l, 16, 0, 0);
}

// 3-deep counted-vmcnt K-loop (128x128 tile kernels; 4 loads/stage).
#define PIPELINE3(NT)                                                         \
  STAGE(0, 0);                                                                \
  if ((NT) > 1) STAGE(32, 1);                                                 \
  if ((NT) > 2) STAGE(64, 2);                                                 \
  {                                                                           \
    int cur = 0;                                                              \
    for (int t = 0; t < (NT); t++) {                                          \
      int rem = (NT) - 1 - t;                                                 \
      if (rem >= 2)      { asm volatile("s_waitcnt vmcnt(8)" ::: "memory"); } \
      else if (rem == 1) { asm volatile("s_waitcnt vmcnt(4)" ::: "memory"); } \
      else               { asm volatile("s_waitcnt vmcnt(0)" ::: "memory"); } \
      asm volatile("s_barrier" ::: "memory");                                 \
      short8 af[4], bfr[4];                                                   \
      _Pragma("unroll")                                                       \
      for (int i = 0; i < 4; i++)                                             \
        af[i] = *(const short8*)(&lA[cur][(wm + i * 16 + fr) * 32 + kh]);     \
      _Pragma("unroll")                                                       \
      for (int j = 0; j < 4; j++)                                             \
        bfr[j] = *(const short8*)(&lB[cur][(wn + j * 16 + fr) * 32 + kh]);    \
      asm volatile("s_waitcnt lgkmcnt(0)" ::: "memory");                      \
      asm volatile("s_barrier" ::: "memory");                                 \
      if (t + 3 < (NT)) STAGE((t + 3) * 32, cur);                             \
      __builtin_amdgcn_s_setprio(1);                                          \
      _Pragma("unroll")                                                       \
      for (int i = 0; i < 4; i++)                                             \
        _Pragma("unroll")                                                     \
        for (int j = 0; j < 4; j++)                                           \
          acc[i][j] = __builtin_amdgcn_mfma_f32_16x16x32_bf16(af[i], bfr[j],  \
                                                              acc[i][j], 0, 0, 0); \
      __builtin_amdgcn_s_setprio(0);                                          \
      cur = (cur == 2) ? 0 : cur + 1;                                         \
    }                                                                         \
  }

// ---------------- upfront convert: emb + all layer weights -> bf16 arena -----
__global__ void k_convert_all(const float* __restrict__ emb, const float* __restrict__ in_w,
                              const float* __restrict__ xp_w, const float* __restrict__ dt_w,
                              const float* __restrict__ out_w, u16* __restrict__ dst) {
  long i0 = ((long)blockIdx.x * 256 + threadIdx.x) * 4;
  if (i0 >= TOTCVT) return;
  us4 o;
#pragma unroll
  for (int q = 0; q < 4; q++) {
    long i = i0 + q;
    float v;
    if (i < EMB_E) {
      long n = i / D_MODEL, k = i % D_MODEL;
      v = (n < VOCAB) ? emb[n * D_MODEL + k] : 0.0f;
    } else {
      long j = i - EMB_E;
      int l = (int)(j / PERL);
      long m = j % PERL;
      if (m < W1E) {
        v = in_w[(long)l * W1E + m];
      } else if (m < W1E + W2E) {
        long mm = m - W1E;
        long n = mm / D_INNER, k = mm % D_INNER;
        v = (n < 80) ? xp_w[(long)l * 80 * D_INNER + n * D_INNER + k] : 0.0f;
      } else if (m < W1E + W2E + W3E) {
        long mm = m - (W1E + W2E);
        long n = mm / 64, k = mm % 64;
        v = (k < DT_RANK) ? dt_w[(long)l * D_INNER * DT_RANK + n * DT_RANK + k] : 0.0f;
      } else {
        long mm = m - (W1E + W2E + W3E);
        v = out_w[(long)l * W4E + mm];
      }
    }
    o[q] = f2bf(v);
  }
  *(us4*)(dst + i0) = o;
}

// ---------------- embed + rmsnorm(layer0) ------------------------------------
__global__ void k_embed_rms(const int* __restrict__ idx, const float* __restrict__ emb,
                            const float* __restrict__ w, float* __restrict__ x,
                            u16* __restrict__ xnb) {
  int t = blockIdx.x, tid = threadIdx.x;
  __shared__ float red[256];
  const float* src = emb + (long)idx[t] * D_MODEL;
  float g[3];
  float s = 0.0f;
#pragma unroll
  for (int q = 0; q < 3; q++) {
    g[q] = src[tid + q * 256];
    s += g[q] * g[q];
  }
  red[tid] = s; __syncthreads();
  for (int o = 128; o > 0; o >>= 1) { if (tid < o) red[tid] += red[tid + o]; __syncthreads(); }
  float scale = rsqrtf(red[0] / (float)D_MODEL + 1e-5f);
#pragma unroll
  for (int q = 0; q < 3; q++) {
    int c = tid + q * 256;
    x[(long)t * D_MODEL + c] = g[q];
    xnb[(long)t * D_MODEL + c] = f2bf(g[q] * scale * w[c]);
  }
}

// ---------------- reduce out_proj partials + residual + rmsnorm --------------
__global__ void k_rms_red(const float* __restrict__ part, const float* __restrict__ w,
                          float* __restrict__ x, u16* __restrict__ xnb) {
  int t = blockIdx.x, tid = threadIdx.x;
  __shared__ float red[256];
  float g[3];
  float s = 0.0f;
#pragma unroll
  for (int q = 0; q < 3; q++) {
    int c = tid + q * 256;
    long off = (long)t * D_MODEL + c;
    float v = x[off];
#pragma unroll
    for (int p = 0; p < 4; p++) v += part[(size_t)p * LSEQ * D_MODEL + off];
    g[q] = v;
    s += v * v;
  }
  red[tid] = s; __syncthreads();
  for (int o = 128; o > 0; o >>= 1) { if (tid < o) red[tid] += red[tid + o]; __syncthreads(); }
  float scale = rsqrtf(red[0] / (float)D_MODEL + 1e-5f);
#pragma unroll
  for (int q = 0; q < 3; q++) {
    int c = tid + q * 256;
    x[(long)t * D_MODEL + c] = g[q];
    xnb[(long)t * D_MODEL + c] = f2bf(g[q] * scale * w[c]);
  }
}

// ---------------- 128x128 3-deep GEMM: C = A(M,K) * W(N,K)^T -----------------
// EPI: 1 = softplus(acc+bias[col]) -> bf16, 2 = bf16 store
template<int EPI>
__global__ __launch_bounds__(256) void k_gemm2(
    const u16* __restrict__ A, const u16* __restrict__ W, void* __restrict__ Cv,
    const float* __restrict__ bias, int N, int K, int lda, int ldb, int ldc) {
  __shared__ u16 lA[3][128 * 32];
  __shared__ u16 lB[3][128 * 32];
  const int gx = gridDim.x, gy = gridDim.y;
  int id = blockIdx.x + gx * blockIdx.y;
  int q8 = (gx * gy) >> 3;
  int v = (id & 7) * q8 + (id >> 3);
  const int bx = v / gy, by = v % gy;
  const int brow = by * 128, bcol = bx * 128;
  const int tid = threadIdx.x, wid = tid >> 6, lane = tid & 63;
  const int wm = (wid >> 1) * 64, wn = (wid & 1) * 64;
  const int fr = lane & 15, fq = lane >> 4;
  const int kh = 8 * (fq ^ ((fr >> 1) & 3));                    // swizzled read slot
  const int srow = tid >> 2;
  const int lcol = (tid & 3) * 8;                               // linear LDS col
  const int scol = 8 * ((tid & 3) ^ ((srow >> 1) & 3));         // swizzled source col
  const u16* ga0 = A + (size_t)(brow + srow) * lda + scol;
  const u16* ga1 = A + (size_t)(brow + srow + 64) * lda + scol;
  const u16* gb0 = W + (size_t)(bcol + srow) * ldb + scol;
  const u16* gb1 = W + (size_t)(bcol + srow + 64) * ldb + scol;
  const int lo = srow * 32 + lcol;

  f32x4 acc[4][4];
#pragma unroll
  for (int i = 0; i < 4; i++)
#pragma unroll
    for (int j = 0; j < 4; j++)
#pragma unroll
      for (int r = 0; r < 4; r++) acc[i][j][r] = 0.0f;

  auto STAGE = [&](int k0, int b) {
    gl16(ga0 + k0, &lA[b][lo]);
    gl16(ga1 + k0, &lA[b][lo + 2048]);
    gl16(gb0 + k0, &lB[b][lo]);
    gl16(gb1 + k0, &lB[b][lo + 2048]);
  };

  PIPELINE3(K / 32);

#pragma unroll
  for (int i = 0; i < 4; i++)
#pragma unroll
    for (int j = 0; j < 4; j++) {
      int col = bcol + wn + j * 16 + fr;
      if (col < N) {
#pragma unroll
        for (int r = 0; r < 4; r++) {
          int row = brow + wm + i * 16 + fq * 4 + r;
          float val = acc[i][j][r];
          if (EPI == 1) {
            val += bias[col];
            val = (val > 20.0f) ? val : log1pf(__expf(val));
            ((u16*)Cv)[(size_t)row * ldc + col] = f2bf(val);
          } else {
            ((u16*)Cv)[(size_t)row * ldc + col] = f2bf(val);
          }
        }
      }
    }
}

// ---------------- split-K partial GEMM (3-deep) ------------------------------
__global__ __launch_bounds__(256) void k_gemm_part(
    const u16* __restrict__ A, const u16* __restrict__ W, float* __restrict__ Cp,
    int N, int Ks, int lda, int ldb, int ldc) {
  __shared__ u16 lA[3][128 * 32];
  __shared__ u16 lB[3][128 * 32];
  const int gx = gridDim.x, gy = gridDim.y;
  int id = blockIdx.x + gx * blockIdx.y;
  int q8 = (gx * gy) >> 3;
  int v = (id & 7) * q8 + (id >> 3);
  const int bx = v / gy, by = v % gy;
  const int brow = by * 128, bcol = bx * 128;
  const int koff = blockIdx.z * Ks;
  const int tid = threadIdx.x, wid = tid >> 6, lane = tid & 63;
  const int wm = (wid >> 1) * 64, wn = (wid & 1) * 64;
  const int fr = lane & 15, fq = lane >> 4;
  const int kh = 8 * (fq ^ ((fr >> 1) & 3));
  const int srow = tid >> 2;
  const int lcol = (tid & 3) * 8;
  const int scol = 8 * ((tid & 3) ^ ((srow >> 1) & 3));
  const u16* ga0 = A + (size_t)(brow + srow) * lda + koff + scol;
  const u16* ga1 = A + (size_t)(brow + srow + 64) * lda + koff + scol;
  const u16* gb0 = W + (size_t)(bcol + srow) * ldb + koff + scol;
  const u16* gb1 = W + (size_t)(bcol + srow + 64) * ldb + koff + scol;
  const int lo = srow * 32 + lcol;

  f32x4 acc[4][4];
#pragma unroll
  for (int i = 0; i < 4; i++)
#pragma unroll
    for (int j = 0; j < 4; j++)
#pragma unroll
      for (int r = 0; r < 4; r++) acc[i][j][r] = 0.0f;

  auto STAGE = [&](int k0, int b) {
    gl16(ga0 + k0, &lA[b][lo]);
    gl16(ga1 + k0, &lA[b][lo + 2048]);
    gl16(gb0 + k0, &lB[b][lo]);
    gl16(gb1 + k0, &lB[b][lo + 2048]);
  };

  PIPELINE3(Ks / 32);

  float* Cz = Cp + (size_t)blockIdx.z * LSEQ * ldc;
#pragma unroll
  for (int i = 0; i < 4; i++)
#pragma unroll
    for (int j = 0; j < 4; j++) {
      int col = bcol + wn + j * 16 + fr;
      if (col < N) {
#pragma unroll
        for (int r = 0; r < 4; r++) {
          int row = brow + wm + i * 16 + fq * 4 + r;
          Cz[(size_t)row * ldc + col] = acc[i][j][r];
        }
      }
    }
}

// ---------------- logits GEMM: 256x128 tile, per-wave 128x64, depth-2 --------
// Best measured config (257-260us). launch_bounds(256,2): acc[8][4] =
// 128 AGPR + ~100 VGPR = 228 regs <= 256 at 2 waves/SIMD; 3 would spill.
__global__ __launch_bounds__(256, 2) void k_gemm_logits(
    const u16* __restrict__ A, const u16* __restrict__ W, float* __restrict__ C,
    float* __restrict__ part) {
  __shared__ u16 lA[2][256 * 32];
  __shared__ u16 lB[2][128 * 32];
  const int b = blockIdx.x;
  const int xcd = b & 7, slot = b >> 3;
  const int ct = xcd * 50 + (slot >> 3), rt = slot & 7;
  const int brow = rt * 256, bcol = ct * 128;
  const int tid = threadIdx.x, wid = tid >> 6, lane = tid & 63;
  const int wm = (wid >> 1) * 128, wn = (wid & 1) * 64;
  const int fr = lane & 15, fq = lane >> 4;
  const int kh = 8 * (fq ^ ((fr >> 1) & 3));
  const int srow = tid >> 2;
  const int lcol = (tid & 3) * 8;
  const int scol = 8 * ((tid & 3) ^ ((srow >> 1) & 3));
  const u16* ga = A + (size_t)(brow + srow) * D_MODEL + scol;
  const u16* gb = W + (size_t)(bcol + srow) * D_MODEL + scol;
  const int lo = srow * 32 + lcol;

  f32x4 acc[8][4];
#pragma unroll
  for (int i = 0; i < 8; i++)
#pragma unroll
    for (int j = 0; j < 4; j++)
#pragma unroll
      for (int r = 0; r < 4; r++) acc[i][j][r] = 0.0f;

  auto STAGE = [&](int k0, int bb) {
    gl16(ga + k0, &lA[bb][lo]);
    gl16(ga + (size_t)64 * D_MODEL + k0, &lA[bb][lo + 2048]);
    gl16(ga + (size_t)128 * D_MODEL + k0, &lA[bb][lo + 4096]);
    gl16(ga + (size_t)192 * D_MODEL + k0, &lA[bb][lo + 6144]);
    gl16(gb + k0, &lB[bb][lo]);
    gl16(gb + (size_t)64 * D_MODEL + k0, &lB[bb][lo + 2048]);
  };

  STAGE(0, 0);
  STAGE(32, 1);
  int cur = 0;
  const int NT = D_MODEL / 32;
  for (int t = 0; t < NT; t++) {
    if (t + 1 < NT) { asm volatile("s_waitcnt vmcnt(6)" ::: "memory"); }
    else            { asm volatile("s_waitcnt vmcnt(0)" ::: "memory"); }
    asm volatile("s_barrier" ::: "memory");
    short8 af[8], bfr[4];
#pragma unroll
    for (int i = 0; i < 8; i++)
      af[i] = *(const short8*)(&lA[cur][(wm + i * 16 + fr) * 32 + kh]);
#pragma unroll
    for (int j = 0; j < 4; j++)
      bfr[j] = *(const short8*)(&lB[cur][(wn + j * 16 + fr) * 32 + kh]);
    asm volatile("s_waitcnt lgkmcnt(0)" ::: "memory");
    asm volatile("s_barrier" ::: "memory");
    if (t + 2 < NT) STAGE((t + 2) * 32, cur);
    __builtin_amdgcn_s_setprio(1);
#pragma unroll
    for (int i = 0; i < 8; i++)
#pragma unroll
      for (int j = 0; j < 4; j++)
        acc[i][j] = __builtin_amdgcn_mfma_f32_16x16x32_bf16(af[i], bfr[j], acc[i][j], 0, 0, 0);
    __builtin_amdgcn_s_setprio(0);
    cur ^= 1;
  }

  float rs[32];
#pragma unroll
  for (int q = 0; q < 32; q++) rs[q] = 0.0f;
#pragma unroll
  for (int i = 0; i < 8; i++)
#pragma unroll
    for (int j = 0; j < 4; j++) {
      int col = bcol + wn + j * 16 + fr;
      if (col < VOCAB) {
#pragma unroll
        for (int r = 0; r < 4; r++) {
          int row = brow + wm + i * 16 + fq * 4 + r;
          float val = acc[i][j][r];
          C[(size_t)row * VOCAB + col] = val;
          rs[i * 4 + r] += __expf(val - 20.0f);
        }
      }
    }
#pragma unroll
  for (int q = 0; q < 32; q++) {
    float s = rs[q];
    s += __shfl_xor(s, 1); s += __shfl_xor(s, 2);
    s += __shfl_xor(s, 4); s += __shfl_xor(s, 8);
    rs[q] = s;
  }
  if (fr == 0) {
    int pc = ct * 2 + (wn >> 6);
#pragma unroll
    for (int i = 0; i < 8; i++)
#pragma unroll
      for (int r = 0; r < 4; r++) {
        int row = brow + wm + i * 16 + fq * 4 + r;
        part[(size_t)pc * LSEQ + row] = rs[i * 4 + r];
      }
  }
}

// ---------------- causal conv1d (K=4) + silu -> bf16, vectorized x8 ----------
__global__ void k_conv_silu(const u16* __restrict__ xzb, const float* __restrict__ cw,
                            const float* __restrict__ cb, u16* __restrict__ xib) {
  int i = blockIdx.x * 256 + threadIdx.x;      // L * D_INNER/8 threads
  int t = i / (D_INNER / 8), d8 = (i % (D_INNER / 8)) * 8;
  float acc[8];
#pragma unroll
  for (int q = 0; q < 8; q++) acc[q] = cb[d8 + q];
#pragma unroll
  for (int k = 0; k < 4; k++) {
    int tt = t - 3 + k;
    if (tt >= 0) {
      short8 v = *(const short8*)(xzb + (long)tt * (2 * D_INNER) + d8);
#pragma unroll
      for (int q = 0; q < 8; q++) acc[q] += bf2f((u16)v[q]) * cw[(d8 + q) * 4 + k];
    }
  }
  short8 o;
#pragma unroll
  for (int q = 0; q < 8; q++) {
    float s = acc[q] / (1.0f + __expf(-acc[q]));
    o[q] = (short)f2bf(s);
  }
  *(short8*)(xib + (long)t * D_INNER + d8) = o;
}

// ---------------- reduce x_proj partials (16) -> xdbl + dt-pad bf16 ----------
__global__ void k_red_xd(const float* __restrict__ pxp, float* __restrict__ xdbl,
                         u16* __restrict__ dtp) {
  int i = blockIdx.x * 256 + threadIdx.x;
  int t = i >> 7, k = i & 127;
  if (k < 80) {
    float s = 0.0f;
#pragma unroll
    for (int p = 0; p < 16; p++) s += pxp[(size_t)p * LSEQ * 80 + (long)t * 80 + k];
    xdbl[(long)t * 80 + k] = s;
    if (k < DT_RANK) dtp[(long)t * 64 + k] = f2bf(s);
    else if (k < 64) dtp[(long)t * 64 + k] = 0;
  }
}

// ---------------- selective scan: 3-phase chunked (dt is bf16) ---------------
__global__ void k_scanA(const u16* __restrict__ dt, const u16* __restrict__ xi,
                        const float* __restrict__ xdbl, const float* __restrict__ a_log,
                        float* __restrict__ aprod, float* __restrict__ hend) {
  int d = blockIdx.x * 256 + threadIdx.x;
  int c = blockIdx.y;
  float A[16], ap[16], h[16];
#pragma unroll
  for (int s = 0; s < 16; s++) { A[s] = -__expf(a_log[d * 16 + s]); ap[s] = 1.0f; h[s] = 0.0f; }
  int t0 = c * TCHUNK;
  for (int t = t0; t < t0 + TCHUNK; t++) {
    float dtv = bf2f(dt[(long)t * D_INNER + d]), xv = bf2f(xi[(long)t * D_INNER + d]);
    float dx = dtv * xv;
    const float* Bp = xdbl + (long)t * 80 + DT_RANK;
#pragma unroll
    for (int s = 0; s < 16; s++) {
      float a = __expf(dtv * A[s]);
      h[s] = a * h[s] + dx * Bp[s];
      ap[s] *= a;
    }
  }
  long base = ((long)c * D_INNER + d) * 16;
#pragma unroll
  for (int s = 0; s < 16; s++) { aprod[base + s] = ap[s]; hend[base + s] = h[s]; }
}

__global__ void k_scanB(const float* __restrict__ aprod, const float* __restrict__ hend,
                        float* __restrict__ hinit) {
  int i = blockIdx.x * 256 + threadIdx.x;
  float h = 0.0f;
  for (int c = 0; c < NCHUNK; c++) {
    long idx = (long)c * D_INNER * 16 + i;
    hinit[idx] = h;
    h = aprod[idx] * h + hend[idx];
  }
}

__global__ void k_scanC(const u16* __restrict__ dt, const u16* __restrict__ xi,
                        const float* __restrict__ xdbl, const float* __restrict__ a_log,
                        const float* __restrict__ hinit, const float* __restrict__ Dp,
                        const u16* __restrict__ xzb, u16* __restrict__ yb) {
  int d = blockIdx.x * 256 + threadIdx.x;
  int c = blockIdx.y;
  float A[16], h[16];
  long hb = (long)c * D_INNER * 16 + (long)d * 16;
#pragma unroll
  for (int s = 0; s < 16; s++) { A[s] = -__expf(a_log[d * 16 + s]); h[s] = hinit[hb + s]; }
  float Dv = Dp[d];
  int t0 = c * TCHUNK;
  for (int t = t0; t < t0 + TCHUNK; t++) {
    float dtv = bf2f(dt[(long)t * D_INNER + d]), xv = bf2f(xi[(long)t * D_INNER + d]);
    float dx = dtv * xv;
    const float* Bp = xdbl + (long)t * 80 + DT_RANK;
    const float* Cp = Bp + D_STATE;
    float o = xv * Dv;
#pragma unroll
    for (int s = 0; s < 16; s++) {
      float a = __expf(dtv * A[s]);
      h[s] = a * h[s] + dx * Bp[s];
      o += h[s] * Cp[s];
    }
    float z = bf2f(xzb[(long)t * (2 * D_INNER) + D_INNER + d]);
    yb[(long)t * D_INNER + d] = f2bf(o * (z / (1.0f + __expf(-z))));
  }
}

// ---------------- final lse from partials + nll (block per token) ------------
__global__ void k_lse_final(const float* __restrict__ part, const float* __restrict__ logits,
                            const int* __restrict__ tgt, float* __restrict__ nll,
                            float* __restrict__ msk) {
  int t = blockIdx.x, tid = threadIdx.x;   // 2048 blocks x 256 threads
  __shared__ float red[256];
  float s = 0.0f;
  for (int p = tid; p < 800; p += 256) s += part[(size_t)p * LSEQ + t];
  red[tid] = s; __syncthreads();
  for (int o = 128; o > 0; o >>= 1) { if (tid < o) red[tid] += red[tid + o]; __syncthreads(); }
  if (tid == 0) {
    float lse = 20.0f + __logf(red[0]);
    int tg = tgt[t];
    float mk = tg >= 0 ? 1.0f : 0.0f;
    int tc = tg < 0 ? 0 : (tg > VOCAB - 1 ? VOCAB - 1 : tg);
    nll[t] = (lse - logits[(size_t)t * VOCAB + tc]) * mk;
    msk[t] = mk;
  }
}

__global__ void k_loss(const float* __restrict__ nll, const float* __restrict__ msk,
                       float* __restrict__ out) {
  int tid = threadIdx.x;
  __shared__ float r1[256], r2[256];
  float a = 0.0f, b = 0.0f;
  for (int i = tid; i < LSEQ; i += 256) { a += nll[i]; b += msk[i]; }
  r1[tid] = a; r2[tid] = b; __syncthreads();
  for (int o = 128; o > 0; o >>= 1) {
    if (tid < o) { r1[tid] += r1[tid + o]; r2[tid] += r2[tid + o]; }
    __syncthreads();
  }
  if (tid == 0) out[0] = r1[0] / fmaxf(r2[0], 1.0f);
}

// =============================================================================
extern "C" void kernel_launch(void* const* d_in, const int* in_sizes, int n_in,
                              void* d_out, int out_size, void* d_ws, size_t ws_size,
                              hipStream_t stream) {
  const int*   idx    = (const int*)d_in[0];
  const int*   tgt    = (const int*)d_in[1];
  const float* emb    = (const float*)d_in[2];
  const float* norm_w = (const float*)d_in[3];
  const float* in_w   = (const float*)d_in[4];
  const float* conv_w = (const float*)d_in[5];
  const float* conv_b = (const float*)d_in[6];
  const float* xp_w   = (const float*)d_in[7];
  const float* dt_w   = (const float*)d_in[8];
  const float* dt_b   = (const float*)d_in[9];
  const float* a_log  = (const float*)d_in[10];
  const float* d_par  = (const float*)d_in[11];
  const float* out_w  = (const float*)d_in[12];
  const float* normf  = (const float*)d_in[13];

  float* logits = (float*)d_out;
  float* loss   = logits + (size_t)LSEQ * VOCAB;

  char* base = (char*)d_ws;
  size_t off = 0;
  auto alloc = [&](size_t bytes) -> char* {
    char* r = base + off;
    off = (off + bytes + 255) & ~(size_t)255;
    return r;
  };
  u16*   wcat = (u16*)  alloc((size_t)TOTCVT * 2);
  float* x    = (float*)alloc((size_t)LSEQ * D_MODEL * 4);
  u16*   xnb  = (u16*)  alloc((size_t)LSEQ * D_MODEL * 2);
  u16*   xzb  = (u16*)  alloc((size_t)LSEQ * 2 * D_INNER * 2);
  u16*   xib  = (u16*)  alloc((size_t)LSEQ * D_INNER * 2);
  float* xdbl = (float*)alloc((size_t)LSEQ * 80 * 4);
  u16*   dtp  = (u16*)  alloc((size_t)LSEQ * 64 * 2);
  u16*   dtl  = (u16*)  alloc((size_t)LSEQ * D_INNER * 2);
  u16*   yb   = (u16*)  alloc((size_t)LSEQ * D_INNER * 2);
  // shared pool: x_proj partials (16x2048x80), out_proj partials (4x2048x768),
  // lse partials (800x2048) — disjoint lifetimes.
  float* pool = (float*)alloc((size_t)4 * LSEQ * D_MODEL * 4);
  float* apr  = (float*)alloc((size_t)NCHUNK * D_INNER * 16 * 4);
  float* hen  = (float*)alloc((size_t)NCHUNK * D_INNER * 16 * 4);
  float* hin  = (float*)alloc((size_t)NCHUNK * D_INNER * 16 * 4);
  float* nll  = (float*)alloc((size_t)LSEQ * 4);
  float* msk  = (float*)alloc((size_t)LSEQ * 4);
  float* pxp  = pool;
  float* pop  = pool;
  float* part = pool;
  (void)ws_size; (void)in_sizes; (void)n_in; (void)out_size;

  const u16* embb = wcat;

  k_convert_all<<<(unsigned)((TOTCVT / 4 + 255) / 256), 256, 0, stream>>>(
      emb, in_w, xp_w, dt_w, out_w, wcat);
  k_embed_rms<<<LSEQ, 256, 0, stream>>>(idx, emb, norm_w, x, xnb);

  for (int l = 0; l < N_LAYER; l++) {
    const u16* w1 = wcat + EMB_E + (long)l * PERL;
    const u16* w2 = w1 + W1E;
    const u16* w3 = w2 + W2E;
    const u16* w4 = w3 + W3E;

    k_gemm2<2><<<dim3(24, 16), 256, 0, stream>>>(
        xnb, w1, xzb, nullptr, 2 * D_INNER, D_MODEL, D_MODEL, D_MODEL, 2 * D_INNER);

    k_conv_silu<<<(LSEQ * D_INNER / 8) / 256, 256, 0, stream>>>(
        xzb, conv_w + (long)l * D_INNER * 4, conv_b + l * D_INNER, xib);

    k_gemm_part<<<dim3(1, 16, 16), 256, 0, stream>>>(
        xib, w2, pxp, 80, D_INNER / 16, D_INNER, D_INNER, 80);
    k_red_xd<<<(LSEQ * 128) / 256, 256, 0, stream>>>(pxp, xdbl, dtp);

    k_gemm2<1><<<dim3(12, 16), 256, 0, stream>>>(
        dtp, w3, dtl, dt_b + l * D_INNER, D_INNER, 64, 64, 64, D_INNER);

    const float* al = a_log + (long)l * D_INNER * D_STATE;
    k_scanA<<<dim3(D_INNER / 256, NCHUNK), 256, 0, stream>>>(dtl, xib, xdbl, al, apr, hen);
    k_scanB<<<(D_INNER * 16) / 256, 256, 0, stream>>>(apr, hen, hin);
    k_scanC<<<dim3(D_INNER / 256, NCHUNK), 256, 0, stream>>>(
        dtl, xib, xdbl, al, hin, d_par + l * D_INNER, xzb, yb);

    k_gemm_part<<<dim3(6, 16, 4), 256, 0, stream>>>(
        yb, w4, pop, D_MODEL, D_INNER / 4, D_INNER, D_INNER, D_MODEL);

    const float* wn = (l < N_LAYER - 1) ? (norm_w + (l + 1) * D_MODEL) : normf;
    k_rms_red<<<LSEQ, 256, 0, stream>>>(pop, wn, x, xnb);
  }

  k_gemm_logits<<<400 * 8, 256, 0, stream>>>(xnb, embb, logits, part);
  k_lse_final<<<LSEQ, 256, 0, stream>>>(part, logits, tgt, nll, msk);
  k_loss<<<1, 256, 0, stream>>>(nll, msk, loss);
}